// Round 1
// baseline (773.161 us; speedup 1.0000x reference)
//
#include <hip/hip_runtime.h>

// Attention_2035814498461 on MI355X (gfx950).
// B=2 N=2048 C=1024 H=16 hd=64, causal mask, outputs (x fp32, attn fp32).
// Strategy: bf16 MFMA for all GEMMs (threshold is bf16-scale), two-pass
// online-normalization attention (recompute QK^T instead of storing S),
// attn written once (537 MB = structural floor ~85us @ 6.3 TB/s).
// Workspace: 56 MB.

typedef unsigned short u16;
typedef unsigned int u32;
typedef __attribute__((ext_vector_type(8))) short s16x8;
typedef __attribute__((ext_vector_type(4))) float f32x4;
typedef __attribute__((ext_vector_type(4))) u16 u16x4;

#define AS1 __attribute__((address_space(1)))
#define AS3 __attribute__((address_space(3)))

static __device__ __forceinline__ u16 f2bf(float f) {
  u32 u = __builtin_bit_cast(u32, f);
  u = (u + 0x7fffu + ((u >> 16) & 1u)) >> 16;
  return (u16)u;
}

static __device__ __forceinline__ void gll16(const u16* g, u16* l) {
  // async global->LDS, 16B per lane; LDS dest must be wave-uniform base + lane*16
  __builtin_amdgcn_global_load_lds((const AS1 u32*)g, (AS3 u32*)l, 16, 0, 0);
}

static __device__ __forceinline__ f32x4 mfma_bf16(s16x8 a, s16x8 b, f32x4 c) {
  return __builtin_amdgcn_mfma_f32_16x16x32_bf16(a, b, c, 0, 0, 0);
}

// ---------------- cast fp32 -> bf16 ----------------
__global__ __launch_bounds__(256) void cast_kernel(const float* __restrict__ in,
                                                   u16* __restrict__ out, int n4) {
  int i = blockIdx.x * 256 + threadIdx.x;
  if (i < n4) {
    f32x4 v = ((const f32x4*)in)[i];
    u16x4 o = { f2bf(v.x), f2bf(v.y), f2bf(v.z), f2bf(v.w) };
    ((u16x4*)out)[i] = o;
  }
}

// ---------------- shared 128x128 BT-GEMM core, K=1024 ----------------
// C[m][n] = sum_k A[m][k]*B[n][k]; A,B bf16 row-major stride 1024.
static __device__ __forceinline__ void gemm_core_1024(
    const u16* __restrict__ A, const u16* __restrict__ Bm,
    int m0, int n0, int t, u16* a_s, u16* b_s, f32x4 acc[4][4]) {
  const int lane = t & 63;
  const int w = t >> 6;
  const int wm = (w & 1) * 64, wn = (w >> 1) * 64;
  const int lrow = lane & 15, lq = lane >> 4;
  const int r0 = t >> 2;          // staging row 0..63
  const int c0 = (t & 3) * 8;     // staging col (elements)

  for (int kt = 0; kt < 1024; kt += 32) {
    __syncthreads();
    gll16(A  + (size_t)(m0 + r0)      * 1024 + kt + c0, &a_s[(size_t)t * 8]);
    gll16(A  + (size_t)(m0 + r0 + 64) * 1024 + kt + c0, &a_s[(size_t)(t + 256) * 8]);
    gll16(Bm + (size_t)(n0 + r0)      * 1024 + kt + c0, &b_s[(size_t)t * 8]);
    gll16(Bm + (size_t)(n0 + r0 + 64) * 1024 + kt + c0, &b_s[(size_t)(t + 256) * 8]);
    __syncthreads();
    s16x8 af[4], bfr[4];
#pragma unroll
    for (int x = 0; x < 4; x++) af[x]  = *(const s16x8*)&a_s[(wm + x*16 + lrow)*32 + lq*8];
#pragma unroll
    for (int x = 0; x < 4; x++) bfr[x] = *(const s16x8*)&b_s[(wn + x*16 + lrow)*32 + lq*8];
#pragma unroll
    for (int tm = 0; tm < 4; tm++)
#pragma unroll
      for (int tn = 0; tn < 4; tn++)
        acc[tm][tn] = mfma_bf16(af[tm], bfr[tn], acc[tm][tn]);
  }
}

// ---------------- QKV projection ----------------
// z=0: Qh[bh][s][d] = SCALE * (q @ wq^T); z=1: Kh[bh][s][d]; z=2: Vt[bh][d][s]
__global__ __launch_bounds__(256) void gemm_qkv_kernel(
    const u16* __restrict__ qb, const u16* __restrict__ kb, const u16* __restrict__ vb,
    const u16* __restrict__ wb, u16* __restrict__ Qh, u16* __restrict__ Kh,
    u16* __restrict__ Vt) {
  __shared__ u16 a_s[128*32], b_s[128*32];
  const int mode = blockIdx.z;
  const u16* A = (mode == 0) ? qb : (mode == 1) ? kb : vb;
  const u16* Bm = wb + (size_t)mode * (1024 * 1024);
  const int m0 = blockIdx.y * 128, n0 = blockIdx.x * 128;
  const int t = threadIdx.x;
  f32x4 acc[4][4];
  const f32x4 Z = {0.f, 0.f, 0.f, 0.f};
#pragma unroll
  for (int i = 0; i < 4; i++)
#pragma unroll
    for (int j = 0; j < 4; j++) acc[i][j] = Z;

  gemm_core_1024(A, Bm, m0, n0, t, a_s, b_s, acc);

  const int lane = t & 63, w = t >> 6;
  const int wm = (w & 1) * 64, wn = (w >> 1) * 64;
  const int lrow = lane & 15, lq = lane >> 4;
#pragma unroll
  for (int tm = 0; tm < 4; tm++) {
#pragma unroll
    for (int tn = 0; tn < 4; tn++) {
      const int ng = n0 + wn + tn * 16 + lrow;
      const int h = ng >> 6, d = ng & 63;
#pragma unroll
      for (int i = 0; i < 4; i++) {
        const int mg = m0 + wm + tm * 16 + lq * 4 + i;
        const int b = mg >> 11, s = mg & 2047;
        const float v = acc[tm][tn][i];
        if (mode == 0)
          Qh[((size_t)(b * 16 + h) * 2048 + s) * 64 + d] = f2bf(v * 0.125f);
        else if (mode == 1)
          Kh[((size_t)(b * 16 + h) * 2048 + s) * 64 + d] = f2bf(v);
        else
          Vt[((size_t)(b * 16 + h) * 64 + d) * 2048 + s] = f2bf(v);
      }
    }
  }
}

// ---------------- output projection (+bias, fp32 out) ----------------
__global__ __launch_bounds__(256) void gemm_proj_kernel(
    const u16* __restrict__ xatt, const u16* __restrict__ pwb,
    const float* __restrict__ bias, float* __restrict__ out) {
  __shared__ u16 a_s[128*32], b_s[128*32];
  const int m0 = blockIdx.y * 128, n0 = blockIdx.x * 128;
  const int t = threadIdx.x;
  f32x4 acc[4][4];
  const f32x4 Z = {0.f, 0.f, 0.f, 0.f};
#pragma unroll
  for (int i = 0; i < 4; i++)
#pragma unroll
    for (int j = 0; j < 4; j++) acc[i][j] = Z;

  gemm_core_1024(xatt, pwb, m0, n0, t, a_s, b_s, acc);

  const int lane = t & 63, w = t >> 6;
  const int wm = (w & 1) * 64, wn = (w >> 1) * 64;
  const int lrow = lane & 15, lq = lane >> 4;
#pragma unroll
  for (int tn = 0; tn < 4; tn++) {
    const int ng = n0 + wn + tn * 16 + lrow;
    const float bv = bias[ng];
#pragma unroll
    for (int tm = 0; tm < 4; tm++) {
#pragma unroll
      for (int i = 0; i < 4; i++) {
        const int mg = m0 + wm + tm * 16 + lq * 4 + i;
        out[(size_t)mg * 1024 + ng] = acc[tm][tn][i] + bv;
      }
    }
  }
}

// ---------------- fused causal attention ----------------
// block = (q-block of 64 rows) x (bh). Pass1: l = sum exp(s) (no max needed,
// scores ~N(0,1) so exp is fp32-safe). Pass2: recompute S, write P to attn,
// LDS round-trip P into A-fragment layout, accumulate O = P@V.
__global__ __launch_bounds__(256) void attn_kernel(
    const u16* __restrict__ Qh, const u16* __restrict__ Kh, const u16* __restrict__ Vt,
    float* __restrict__ attn, u16* __restrict__ xatt, const int* __restrict__ use_mask_p) {
  __shared__ u16 q_s[64*64], k_s[64*64], v_s[64*64];
  __shared__ u16 p_s[4][16*64];   // wave-private P tiles

  const int bh = blockIdx.y;
  const int q0 = blockIdx.x * 64;
  const int t = threadIdx.x;
  const int lane = t & 63, w = t >> 6;
  const int lrow = lane & 15, lq = lane >> 4;
  const int use_mask = *use_mask_p;
  const int T = use_mask ? (q0 >> 6) : 31;   // last j-tile index

  const int rs = t >> 3;           // staging row 0..31
  const int cs = (t & 7) * 8;      // staging col (elements)

  // stage Q (64x64) once
  const u16* qg = Qh + ((size_t)bh * 2048 + q0) * 64;
  gll16(qg + (size_t)rs * 64 + cs,        &q_s[(size_t)t * 8]);
  gll16(qg + (size_t)(rs + 32) * 64 + cs, &q_s[(size_t)(t + 256) * 8]);
  __syncthreads();

  s16x8 qf[2];
#pragma unroll
  for (int kq = 0; kq < 2; kq++)
    qf[kq] = *(const s16x8*)&q_s[(w * 16 + lrow) * 64 + kq * 32 + lq * 8];

  const u16* kg = Kh + (size_t)bh * (2048 * 64);
  const u16* vg = Vt + (size_t)bh * (64 * 2048);

  // ---- pass 1: row sums l ----
  float l_acc[4] = {0.f, 0.f, 0.f, 0.f};
  for (int tt = 0; tt <= T; tt++) {
    __syncthreads();
    gll16(kg + (size_t)(tt * 64 + rs) * 64 + cs,      &k_s[(size_t)t * 8]);
    gll16(kg + (size_t)(tt * 64 + rs + 32) * 64 + cs, &k_s[(size_t)(t + 256) * 8]);
    __syncthreads();
    f32x4 sacc[4];
    const f32x4 Z = {0.f, 0.f, 0.f, 0.f};
#pragma unroll
    for (int tn = 0; tn < 4; tn++) {
      sacc[tn] = Z;
#pragma unroll
      for (int kq = 0; kq < 2; kq++) {
        s16x8 kf = *(const s16x8*)&k_s[(tn * 16 + lrow) * 64 + kq * 32 + lq * 8];
        sacc[tn] = mfma_bf16(qf[kq], kf, sacc[tn]);
      }
    }
    const bool diag = use_mask && (tt == T);
    float part[4] = {0.f, 0.f, 0.f, 0.f};
#pragma unroll
    for (int tn = 0; tn < 4; tn++)
#pragma unroll
      for (int i = 0; i < 4; i++) {
        const bool ok = !diag || (tn * 16 + lrow <= w * 16 + lq * 4 + i);
        part[i] += ok ? __expf(sacc[tn][i]) : 0.f;
      }
#pragma unroll
    for (int i = 0; i < 4; i++) {
      float p = part[i];
      p += __shfl_xor(p, 1, 16);
      p += __shfl_xor(p, 2, 16);
      p += __shfl_xor(p, 4, 16);
      p += __shfl_xor(p, 8, 16);
      l_acc[i] += p;
    }
  }
  float inv_l[4];
#pragma unroll
  for (int i = 0; i < 4; i++) inv_l[i] = 1.0f / l_acc[i];

  // ---- pass 2: P write + O = P@V ----
  f32x4 oacc[4];
  const f32x4 Z = {0.f, 0.f, 0.f, 0.f};
#pragma unroll
  for (int i = 0; i < 4; i++) oacc[i] = Z;

  for (int tt = 0; tt <= T; tt++) {
    __syncthreads();
    gll16(kg + (size_t)(tt * 64 + rs) * 64 + cs,      &k_s[(size_t)t * 8]);
    gll16(kg + (size_t)(tt * 64 + rs + 32) * 64 + cs, &k_s[(size_t)(t + 256) * 8]);
    gll16(vg + (size_t)rs * 2048 + tt * 64 + cs,        &v_s[(size_t)t * 8]);
    gll16(vg + (size_t)(rs + 32) * 2048 + tt * 64 + cs, &v_s[(size_t)(t + 256) * 8]);
    __syncthreads();
    f32x4 sacc[4];
#pragma unroll
    for (int tn = 0; tn < 4; tn++) {
      sacc[tn] = Z;
#pragma unroll
      for (int kq = 0; kq < 2; kq++) {
        s16x8 kf = *(const s16x8*)&k_s[(tn * 16 + lrow) * 64 + kq * 32 + lq * 8];
        sacc[tn] = mfma_bf16(qf[kq], kf, sacc[tn]);
      }
    }
    const bool diag = use_mask && (tt == T);
    float* abase = attn + ((size_t)(bh * 2048 + q0 + w * 16)) * 2048 + tt * 64;
#pragma unroll
    for (int tn = 0; tn < 4; tn++)
#pragma unroll
      for (int i = 0; i < 4; i++) {
        const bool ok = !diag || (tn * 16 + lrow <= w * 16 + lq * 4 + i);
        const float p = ok ? __expf(sacc[tn][i]) * inv_l[i] : 0.f;
        const int rl = lq * 4 + i;
        abase[(size_t)rl * 2048 + tn * 16 + lrow] = p;
        p_s[w][rl * 64 + tn * 16 + lrow] = f2bf(p);
      }
    // P (C/D layout) -> A-operand layout via wave-private LDS, then PV
    s16x8 pf[2];
#pragma unroll
    for (int kq = 0; kq < 2; kq++)
      pf[kq] = *(const s16x8*)&p_s[w][lrow * 64 + kq * 32 + lq * 8];
#pragma unroll
    for (int td = 0; td < 4; td++)
#pragma unroll
      for (int kq = 0; kq < 2; kq++) {
        s16x8 vf = *(const s16x8*)&v_s[(td * 16 + lrow) * 64 + kq * 32 + lq * 8];
        oacc[td] = mfma_bf16(pf[kq], vf, oacc[td]);
      }
  }

  // O -> xatt (B,N,C) bf16
  const int b = bh >> 4, h = bh & 15;
#pragma unroll
  for (int td = 0; td < 4; td++)
#pragma unroll
    for (int i = 0; i < 4; i++) {
      const int row = q0 + w * 16 + lq * 4 + i;
      xatt[((size_t)(b * 2048 + row)) * 1024 + h * 64 + td * 16 + lrow] = f2bf(oacc[td][i]);
    }

  // zero-fill the masked upper region of attn (reference softmax gives exact 0)
  if (use_mask) {
    const int zc0 = q0 + 64;
    if (zc0 < 2048) {
      const int nzv = (2048 - zc0) >> 2;   // float4s per row
      f32x4* zb = (f32x4*)(attn + ((size_t)bh * 2048 + q0) * 2048 + zc0);
      const int row = t >> 2;
      const f32x4 Z4 = {0.f, 0.f, 0.f, 0.f};
      for (int c = (t & 3); c < nzv; c += 4)
        zb[(size_t)row * 512 + c] = Z4;
    }
  }
}

extern "C" void kernel_launch(void* const* d_in, const int* in_sizes, int n_in,
                              void* d_out, int out_size, void* d_ws, size_t ws_size,
                              hipStream_t stream) {
  const float* q      = (const float*)d_in[0];
  const float* k      = (const float*)d_in[1];
  const float* v      = (const float*)d_in[2];
  const float* qkv_w  = (const float*)d_in[3];
  const float* proj_w = (const float*)d_in[4];
  const float* proj_b = (const float*)d_in[5];
  const int*   use_mask = (const int*)d_in[6];

  const size_t MB = 1024 * 1024;
  char* ws = (char*)d_ws;
  u16* qb  = (u16*)(ws + 0 * MB);   // 8 MB (reused as xatt after QKV gemm)
  u16* kb  = (u16*)(ws + 8 * MB);   // 8 MB
  u16* vb  = (u16*)(ws + 16 * MB);  // 8 MB
  u16* wb  = (u16*)(ws + 24 * MB);  // 6 MB
  u16* pwb = (u16*)(ws + 30 * MB);  // 2 MB
  u16* Qh  = (u16*)(ws + 32 * MB);  // 8 MB
  u16* Kh  = (u16*)(ws + 40 * MB);  // 8 MB
  u16* Vt  = (u16*)(ws + 48 * MB);  // 8 MB
  u16* xat = qb;                    // qb dead after gemm_qkv; reuse

  float* out_x    = (float*)d_out;
  float* out_attn = out_x + (size_t)2 * 2048 * 1024;

  cast_kernel<<<4096, 256, 0, stream>>>(q, qb, 1048576);
  cast_kernel<<<4096, 256, 0, stream>>>(k, kb, 1048576);
  cast_kernel<<<4096, 256, 0, stream>>>(v, vb, 1048576);
  cast_kernel<<<3072, 256, 0, stream>>>(qkv_w, wb, 786432);
  cast_kernel<<<1024, 256, 0, stream>>>(proj_w, pwb, 262144);

  gemm_qkv_kernel<<<dim3(8, 32, 3), 256, 0, stream>>>(qb, kb, vb, wb, Qh, Kh, Vt);
  attn_kernel<<<dim3(32, 32), 256, 0, stream>>>(Qh, Kh, Vt, out_attn, xat, use_mask);
  gemm_proj_kernel<<<dim3(8, 32), 256, 0, stream>>>(xat, pwb, proj_b, out_x);
}